// Round 15
// baseline (203.801 us; speedup 1.0000x reference)
//
#include <hip/hip_runtime.h>
#include <hip/hip_bf16.h>

#define N_FINE   16384
#define S_COARSE 4096
#define DC       256
#define DF       64
#define K1       320   // DC + DF
#define C1       256
#define C2       128
#define BIGF     1e8f
#define EPS_W    1e-8f
#define EPS_BN   1e-5f
#define IMAX     0x7fffffff

typedef __attribute__((ext_vector_type(8))) short bf16x8;
typedef __attribute__((ext_vector_type(8))) unsigned short u16x8;
typedef __attribute__((ext_vector_type(4))) float f32x4;

// ---------------- workspace layout (bytes) ----------------
#define OFF_RANGES 0          // 8 ints
#define OFF_SUMS   256        // sums1[256] sumsq1[256] sums2[128] sumsq2[128]
#define OFF_CPACK  8192       // 4096 * float4
#define OFF_CFT    73728      // 4096*256*4 = 4 MiB
#define OFF_W1B    4268032    // 256*320*2 = 160 KiB (bf16)
#define OFF_W2B    4431872    // 128*256*2 = 64 KiB (bf16)
#define OFF_Y1     4497408    // 16384*256*2 = 8 MiB (bf16)
#define OFF_Y2     12886016   // 16384*128*4 = 8 MiB (f32)

__device__ inline unsigned short f2bf_bits(float f) {
    __hip_bfloat16 h = __float2bfloat16(f);
    unsigned short u;
    __builtin_memcpy(&u, &h, 2);
    return u;
}
__device__ inline float bf2f(unsigned short u) {
    return __uint_as_float(((unsigned)u) << 16);
}

// ---------------- fused setup: range | zero sums | pack | cvtw | transpose ----------------
__global__ __launch_bounds__(256) void setup_kernel(
    const int* __restrict__ cid, int* __restrict__ ranges, float* __restrict__ sums,
    const float* __restrict__ cxyz, float4* __restrict__ cpack,
    const float* __restrict__ W1, const float* __restrict__ W2,
    unsigned short* __restrict__ W1b, unsigned short* __restrict__ W2b,
    const float* __restrict__ cf, float* __restrict__ cfT)
{
    __shared__ float tile[32][33];
    int b = blockIdx.x, t = threadIdx.x;
    if (b == 0) {
        if (t < 8) ranges[t] = 0;
        for (int i = t; i < 768; i += 256) sums[i] = 0.f;
        __syncthreads();
        for (int s = t; s < S_COARSE; s += 256) {
            int c = cid[s];
            if (s == 0 || cid[s - 1] != c) ranges[c] = s;
            if (s == S_COARSE - 1 || cid[s + 1] != c) ranges[4 + c] = s + 1;
        }
    } else if (b <= 16) {
        int s = (b - 1) * 256 + t;
        float x = cxyz[s], y = cxyz[S_COARSE + s], z = cxyz[2 * S_COARSE + s];
        cpack[s] = make_float4(x, y, z, x * x + y * y + z * z);
    } else if (b <= 336) {
        int i = (b - 17) * 256 + t;
        W1b[i] = f2bf_bits(W1[i]);
        if (i < C2 * C1) W2b[i] = f2bf_bits(W2[i]);
    } else {
        int lb = b - 337;
        int tx = t & 31, ty = t >> 5;
        int s0 = (lb & 127) * 32, c0 = (lb >> 7) * 32;
        #pragma unroll
        for (int i = 0; i < 4; i++)
            tile[ty + i * 8][tx] = cf[(c0 + ty + i * 8) * S_COARSE + s0 + tx];
        __syncthreads();
        #pragma unroll
        for (int i = 0; i < 4; i++) {
            int s = ty + i * 8;
            cfT[(s0 + s) * DC + c0 + tx] = tile[tx][s];
        }
    }
}

// ---------------- mega gemm1: in-block 3-NN + interp + GEMM1 + stats ----------------
// BM=32, BN=256, grid 512, 4 waves. Phase 1: each wave computes 3-NN for 8 of the
// block's 32 points (lex-comparator butterfly == jax top_k tie-breaking), results to
// LDS. Phase 2: software-pipelined interp-gather + MFMA GEMM (round-11 structure).
__global__ __launch_bounds__(256) void gemm1_kernel(
    const float* __restrict__ fxyz, const int* __restrict__ fpid,
    const float4* __restrict__ cpack, const int* __restrict__ ranges,
    const float* __restrict__ cfT, const float* __restrict__ ff,
    const unsigned short* __restrict__ W1b, const float* __restrict__ bias,
    unsigned short* __restrict__ Y1, float* __restrict__ sums, float* __restrict__ sumsq)
{
    __shared__ __align__(16) unsigned short As[4 * 32 * 8];   // 2 KiB
    __shared__ __align__(16) unsigned short Bs[4 * 256 * 8];  // 16 KiB
    __shared__ int   sI[32][3];
    __shared__ float sWt[32][3];
    int t = threadIdx.x;
    int m0 = blockIdx.x * 32;
    int lane = t & 63, wid = t >> 6;
    int wn = wid * 64;

    // ---- phase 1: 3-NN for this block's points (wave wid -> points wid*8..wid*8+7)
    for (int pp = 0; pp < 8; ++pp) {
        int p = wid * 8 + pp;
        int n = m0 + p;
        int fid = fpid[n];
        float fx = fxyz[n], fy = fxyz[N_FINE + n], fz = fxyz[2 * N_FINE + n];
        float fn2 = fx * fx + fy * fy + fz * fz;
        int st = ranges[fid], en = ranges[4 + fid];
        float d0 = BIGF, d1 = BIGF, d2v = BIGF;
        int i0 = IMAX, i1 = IMAX, i2 = IMAX;
        for (int s = st + lane; s < en; s += 64) {
            float4 c = cpack[s];
            float d = fn2 + c.w - 2.0f * (fx * c.x + fy * c.y + fz * c.z);
            if (d < d0)       { d2v = d1; i2 = i1; d1 = d0; i1 = i0; d0 = d; i0 = s; }
            else if (d < d1)  { d2v = d1; i2 = i1; d1 = d;  i1 = s; }
            else if (d < d2v) { d2v = d;  i2 = s; }
        }
        #pragma unroll
        for (int m = 1; m < 64; m <<= 1) {
            float e0 = __shfl_xor(d0, m, 64), e1 = __shfl_xor(d1, m, 64), e2 = __shfl_xor(d2v, m, 64);
            int   j0 = __shfl_xor(i0, m, 64), j1 = __shfl_xor(i1, m, 64), j2 = __shfl_xor(i2, m, 64);
            #pragma unroll
            for (int q = 0; q < 3; q++) {
                float e = (q == 0) ? e0 : (q == 1) ? e1 : e2;
                int   j = (q == 0) ? j0 : (q == 1) ? j1 : j2;
                bool b0 = (e < d0) || (e == d0 && j < i0);
                bool b1 = (e < d1) || (e == d1 && j < i1);
                bool b2 = (e < d2v) || (e == d2v && j < i2);
                if (b0)      { d2v = d1; i2 = i1; d1 = d0; i1 = i0; d0 = e; i0 = j; }
                else if (b1) { d2v = d1; i2 = i1; d1 = e;  i1 = j; }
                else if (b2) { d2v = e;  i2 = j; }
            }
        }
        if (lane == 0) {
            int cand = 0;
            while (i0 == IMAX || i1 == IMAX || i2 == IMAX) {
                if (cand >= st && cand < en) { cand = en; continue; }
                if (i0 == IMAX)      { i0 = cand; d0 = BIGF; }
                else if (i1 == IMAX) { i1 = cand; d1 = BIGF; }
                else                 { i2 = cand; d2v = BIGF; }
                cand++;
            }
            float w0 = 1.0f / (d0 + EPS_W);
            float w1 = 1.0f / (d1 + EPS_W);
            float w2 = 1.0f / (d2v + EPS_W);
            float inv = 1.0f / (w0 + w1 + w2);
            sI[p][0] = i0; sI[p][1] = i1; sI[p][2] = i2;
            sWt[p][0] = w0 * inv; sWt[p][1] = w1 * inv; sWt[p][2] = w2 * inv;
        }
    }
    __syncthreads();   // sI/sWt visible to all

    // ---- phase 2: pipelined interp + GEMM
    int ksA = t & 3, rowA = t >> 2;          // A staging: threads 0..127
    int fxw = ksA << 2;
    int gA = ksA * 32 + (rowA ^ fxw);
    int rowB = t;                             // B staging: each thread one W1 row
    f32x4 acc[2][4] = {};
    int ks = lane >> 4, r16 = lane & 15, fxr = ks << 2;

    const float *c0p = nullptr, *c1p = nullptr, *c2p = nullptr;
    float w0v = 0.f, w1v = 0.f, w2v = 0.f;
    if (t < 128) {
        c0p = &cfT[sI[rowA][0] * DC];
        c1p = &cfT[sI[rowA][1] * DC];
        c2p = &cfT[sI[rowA][2] * DC];
        w0v = sWt[rowA][0]; w1v = sWt[rowA][1]; w2v = sWt[rowA][2];
    }
    const unsigned short* pb = &W1b[(size_t)rowB * K1];

    float r[24];
    u16x8 vb[4];
    {
        int k0 = ksA * 8;       // < DC always
        if (t < 128) {
            *(float4*)&r[0]  = *(const float4*)(c0p + k0);
            *(float4*)&r[4]  = *(const float4*)(c0p + k0 + 4);
            *(float4*)&r[8]  = *(const float4*)(c1p + k0);
            *(float4*)&r[12] = *(const float4*)(c1p + k0 + 4);
            *(float4*)&r[16] = *(const float4*)(c2p + k0);
            *(float4*)&r[20] = *(const float4*)(c2p + k0 + 4);
        }
        #pragma unroll
        for (int kb = 0; kb < 4; kb++) vb[kb] = *(const u16x8*)(pb + kb * 8);
    }

    #pragma unroll
    for (int kt = 0; kt < K1; kt += 32) {
        u16x8 va;
        if (t < 128) {
            int k0 = kt + ksA * 8;
            if (k0 < DC) {
                #pragma unroll
                for (int i = 0; i < 8; i++)
                    va[i] = f2bf_bits(w0v * r[i] + w1v * r[8 + i] + w2v * r[16 + i]);
            } else {
                #pragma unroll
                for (int i = 0; i < 8; i++)
                    va[i] = f2bf_bits(r[i]);
            }
        }
        float rn[24];
        u16x8 vbn[4];
        if (kt + 32 < K1) {
            int k0n = kt + 32 + ksA * 8;
            if (t < 128) {
                if (k0n < DC) {
                    *(float4*)&rn[0]  = *(const float4*)(c0p + k0n);
                    *(float4*)&rn[4]  = *(const float4*)(c0p + k0n + 4);
                    *(float4*)&rn[8]  = *(const float4*)(c1p + k0n);
                    *(float4*)&rn[12] = *(const float4*)(c1p + k0n + 4);
                    *(float4*)&rn[16] = *(const float4*)(c2p + k0n);
                    *(float4*)&rn[20] = *(const float4*)(c2p + k0n + 4);
                } else {
                    int c = k0n - DC;
                    #pragma unroll
                    for (int i = 0; i < 8; i++)
                        rn[i] = ff[(size_t)(c + i) * N_FINE + m0 + rowA];
                }
            }
            #pragma unroll
            for (int kb = 0; kb < 4; kb++)
                vbn[kb] = *(const u16x8*)(pb + kt + 32 + kb * 8);
        }
        __syncthreads();   // previous iteration's frag reads complete
        if (t < 128) *(u16x8*)&As[gA * 8] = va;
        #pragma unroll
        for (int kb = 0; kb < 4; kb++)
            *(u16x8*)&Bs[(kb * 256 + (rowB ^ (kb << 2))) * 8] = vb[kb];
        __syncthreads();
        bf16x8 af[2], bfr[4];
        #pragma unroll
        for (int mi = 0; mi < 2; mi++)
            af[mi] = *(const bf16x8*)&As[(ks * 32 + ((mi * 16 + r16) ^ fxr)) * 8];
        #pragma unroll
        for (int nj = 0; nj < 4; nj++)
            bfr[nj] = *(const bf16x8*)&Bs[(ks * 256 + ((wn + nj * 16 + r16) ^ fxr)) * 8];
        #pragma unroll
        for (int mi = 0; mi < 2; mi++)
            #pragma unroll
            for (int nj = 0; nj < 4; nj++)
                acc[mi][nj] = __builtin_amdgcn_mfma_f32_16x16x32_bf16(af[mi], bfr[nj], acc[mi][nj], 0, 0, 0);
        if (kt + 32 < K1) {
            #pragma unroll
            for (int i = 0; i < 24; i++) r[i] = rn[i];
            #pragma unroll
            for (int kb = 0; kb < 4; kb++) vb[kb] = vbn[kb];
        }
    }

    // epilogue: C/D layout col(n)=lane&15, row(m)=4*(lane>>4)+reg  [m89/m91]
    float sl[4] = {0.f, 0.f, 0.f, 0.f}, s2l[4] = {0.f, 0.f, 0.f, 0.f};
    #pragma unroll
    for (int nj = 0; nj < 4; nj++) {
        int n = wn + nj * 16 + r16;
        float bb = bias[n];
        #pragma unroll
        for (int mi = 0; mi < 2; mi++) {
            #pragma unroll
            for (int r4 = 0; r4 < 4; r4++) {
                int m = m0 + mi * 16 + ks * 4 + r4;
                float o = acc[mi][nj][r4] + bb;
                Y1[(size_t)m * C1 + n] = f2bf_bits(o);
                sl[nj] += o; s2l[nj] += o * o;
            }
        }
    }
    #pragma unroll
    for (int nj = 0; nj < 4; nj++) {
        sl[nj]  += __shfl_xor(sl[nj],  16, 64);
        sl[nj]  += __shfl_xor(sl[nj],  32, 64);
        s2l[nj] += __shfl_xor(s2l[nj], 16, 64);
        s2l[nj] += __shfl_xor(s2l[nj], 32, 64);
    }
    if (lane < 16) {
        #pragma unroll
        for (int nj = 0; nj < 4; nj++) {
            atomicAdd(&sums[wn + nj * 16 + lane],  sl[nj]);
            atomicAdd(&sumsq[wn + nj * 16 + lane], s2l[nj]);
        }
    }
}

// ---------------- gemm2: in-prologue finalize1 + BN1+ReLU on A + stats2 ----------------
// BM=64, BN=64 -> grid (256,2)=512 blocks, 4 waves. sums1 complete at launch (stream
// order) so each block computes scale1/shift1 itself -> LDS (kills finalize1 dispatch).
template <int KDIM, int NOUT>
__global__ __launch_bounds__(256) void mfma_gemm2_kernel(
    const unsigned short* __restrict__ A,   // [M][KDIM] bf16 bits
    const unsigned short* __restrict__ B,   // [NOUT][KDIM] bf16 bits
    const float* __restrict__ bias,
    const float* __restrict__ sums1, const float* __restrict__ sumsq1,
    const float* __restrict__ g1, const float* __restrict__ be1,
    float* __restrict__ Yout,
    float* __restrict__ sums, float* __restrict__ sumsq)
{
    __shared__ __align__(16) unsigned short As[4 * 64 * 8];  // 4 KiB
    __shared__ __align__(16) unsigned short Bs[4 * 64 * 8];  // 4 KiB
    __shared__ float sSc[KDIM], sSh[KDIM];                   // 2 KiB
    int t = threadIdx.x;
    int m0 = blockIdx.x * 64, j0 = blockIdx.y * 64;
    int lane = t & 63, wid = t >> 6;
    int wm = (wid >> 1) * 32, wn = (wid & 1) * 32;

    // finalize1 in-prologue (KDIM == C1 == 256 == blockDim)
    {
        float mean = sums1[t] * (1.0f / N_FINE);
        float var = sumsq1[t] * (1.0f / N_FINE) - mean * mean;
        float sc = g1[t] * rsqrtf(var + EPS_BN);
        sSc[t] = sc;
        sSh[t] = be1[t] - mean * sc;
    }

    int ksA = t & 3;
    int rowA = t >> 2;                 // 0..63
    int fxw = ksA << 2;
    int gA = ksA * 64 + (rowA ^ fxw);
    const unsigned short* pa = A + (size_t)(m0 + rowA) * KDIM + ksA * 8;
    const unsigned short* pb = B + (size_t)(j0 + rowA) * KDIM + ksA * 8;

    f32x4 acc[2][2] = {};
    int ks = lane >> 4, r16 = lane & 15;
    int fxr = ks << 2;

    u16x8 va = *(const u16x8*)pa;
    u16x8 vb = *(const u16x8*)pb;
    __syncthreads();   // sSc/sSh visible

    #pragma unroll
    for (int kt = 0; kt < KDIM; kt += 32) {
        // BN1+ReLU transform on current A (scale/shift from LDS)
        u16x8 vat;
        {
            int kb = kt + ksA * 8;
            #pragma unroll
            for (int i = 0; i < 8; i++)
                vat[i] = f2bf_bits(fmaxf(fmaf(bf2f(va[i]), sSc[kb + i], sSh[kb + i]), 0.f));
        }
        u16x8 van, vbn;
        if (kt + 32 < KDIM) {
            van = *(const u16x8*)(pa + kt + 32);
            vbn = *(const u16x8*)(pb + kt + 32);
        }
        __syncthreads();
        *(u16x8*)&As[gA * 8] = vat;
        *(u16x8*)&Bs[gA * 8] = vb;
        __syncthreads();
        bf16x8 af[2], bfr[2];
        #pragma unroll
        for (int mi = 0; mi < 2; mi++)
            af[mi] = *(const bf16x8*)&As[(ks * 64 + ((wm + mi * 16 + r16) ^ fxr)) * 8];
        #pragma unroll
        for (int nj = 0; nj < 2; nj++)
            bfr[nj] = *(const bf16x8*)&Bs[(ks * 64 + ((wn + nj * 16 + r16) ^ fxr)) * 8];
        #pragma unroll
        for (int mi = 0; mi < 2; mi++)
            #pragma unroll
            for (int nj = 0; nj < 2; nj++)
                acc[mi][nj] = __builtin_amdgcn_mfma_f32_16x16x32_bf16(af[mi], bfr[nj], acc[mi][nj], 0, 0, 0);
        if (kt + 32 < KDIM) { va = van; vb = vbn; }
    }

    float sl[2] = {0.f, 0.f}, s2l[2] = {0.f, 0.f};
    #pragma unroll
    for (int nj = 0; nj < 2; nj++) {
        int n = j0 + wn + nj * 16 + r16;
        float bb = bias[n];
        #pragma unroll
        for (int mi = 0; mi < 2; mi++) {
            #pragma unroll
            for (int r4 = 0; r4 < 4; r4++) {
                int m = m0 + wm + mi * 16 + ks * 4 + r4;
                float o = acc[mi][nj][r4] + bb;
                Yout[(size_t)m * NOUT + n] = o;
                sl[nj] += o; s2l[nj] += o * o;
            }
        }
    }
    #pragma unroll
    for (int nj = 0; nj < 2; nj++) {
        sl[nj]  += __shfl_xor(sl[nj],  16, 64);
        sl[nj]  += __shfl_xor(sl[nj],  32, 64);
        s2l[nj] += __shfl_xor(s2l[nj], 16, 64);
        s2l[nj] += __shfl_xor(s2l[nj], 32, 64);
    }
    if (lane < 16) {
        atomicAdd(&sums[j0 + wn + lane],       sl[0]);
        atomicAdd(&sums[j0 + wn + 16 + lane],  sl[1]);
        atomicAdd(&sumsq[j0 + wn + lane],      s2l[0]);
        atomicAdd(&sumsq[j0 + wn + 16 + lane], s2l[1]);
    }
}

// ---------------- out: in-prologue finalize2 + BN2+ReLU + transposed store ----------------
__global__ __launch_bounds__(256) void out_kernel(const float* __restrict__ Y2,
                                                  const float* __restrict__ sums2,
                                                  const float* __restrict__ sumsq2,
                                                  const float* __restrict__ g2,
                                                  const float* __restrict__ be2,
                                                  float* __restrict__ out) {
    __shared__ float tile[64][65];
    __shared__ float sSc[64], sSh[64];
    int t = threadIdx.x;
    int n0 = blockIdx.x * 64, c0 = blockIdx.y * 64;
    if (t < 64) {
        int c = c0 + t;
        float mean = sums2[c] * (1.0f / N_FINE);
        float var = sumsq2[c] * (1.0f / N_FINE) - mean * mean;
        float sc = g2[c] * rsqrtf(var + EPS_BN);
        sSc[t] = sc;
        sSh[t] = be2[c] - mean * sc;
    }
    int cl = t & 63, rg = t >> 6;
    #pragma unroll
    for (int i = 0; i < 16; i++) {
        int r = rg + i * 4;
        tile[r][cl] = Y2[(n0 + r) * C2 + c0 + cl];
    }
    __syncthreads();
    #pragma unroll
    for (int i = 0; i < 16; i++) {
        int c = rg + i * 4;
        float v = fmaf(tile[cl][c], sSc[c], sSh[c]);
        out[(c0 + c) * N_FINE + n0 + cl] = fmaxf(v, 0.f);
    }
}

extern "C" void kernel_launch(void* const* d_in, const int* in_sizes, int n_in,
                              void* d_out, int out_size, void* d_ws, size_t ws_size,
                              hipStream_t stream) {
    const float* fine_xyz   = (const float*)d_in[0];
    const float* coarse_xyz = (const float*)d_in[1];
    const int*   fine_pid   = (const int*)d_in[2];
    const int*   coarse_pid = (const int*)d_in[3];
    const float* fine_feat  = (const float*)d_in[4];
    const float* coarse_feat= (const float*)d_in[5];
    const float* W1  = (const float*)d_in[6];
    const float* b1  = (const float*)d_in[7];
    const float* g1  = (const float*)d_in[8];
    const float* be1 = (const float*)d_in[9];
    const float* W2  = (const float*)d_in[10];
    const float* b2  = (const float*)d_in[11];
    const float* g2  = (const float*)d_in[12];
    const float* be2 = (const float*)d_in[13];
    float* out = (float*)d_out;

    char* ws = (char*)d_ws;
    int*    ranges = (int*)(ws + OFF_RANGES);
    float*  sums1  = (float*)(ws + OFF_SUMS);
    float*  sumsq1 = sums1 + 256;
    float*  sums2  = sums1 + 512;
    float*  sumsq2 = sums1 + 640;
    float4* cpack  = (float4*)(ws + OFF_CPACK);
    float*  cfT    = (float*)(ws + OFF_CFT);
    unsigned short* W1b = (unsigned short*)(ws + OFF_W1B);
    unsigned short* W2b = (unsigned short*)(ws + OFF_W2B);
    unsigned short* Y1  = (unsigned short*)(ws + OFF_Y1);
    float*          Y2  = (float*)(ws + OFF_Y2);

    setup_kernel<<<1361, 256, 0, stream>>>(coarse_pid, ranges, sums1,
                                           coarse_xyz, cpack, W1, W2, W1b, W2b,
                                           coarse_feat, cfT);

    gemm1_kernel<<<N_FINE / 32, 256, 0, stream>>>(fine_xyz, fine_pid, cpack, ranges,
                                                  cfT, fine_feat, W1b, b1,
                                                  Y1, sums1, sumsq1);

    mfma_gemm2_kernel<C1, C2><<<dim3(N_FINE / 64, C2 / 64), 256, 0, stream>>>(
        Y1, W2b, b2, sums1, sumsq1, g1, be1, Y2, sums2, sumsq2);

    out_kernel<<<dim3(N_FINE / 64, C2 / 64), 256, 0, stream>>>(Y2, sums2, sumsq2,
                                                               g2, be2, out);
}